// Round 8
// baseline (493.821 us; speedup 1.0000x reference)
//
#include <hip/hip_runtime.h>
#include <stdint.h>

// Problem constants
#define E_DIM 1024
#define KAUG 1056            // 1024 + 16 (LoRA) + 1 (bias) + 15 pad
#define N_HEADS 16
#define HD 64
#define R_LORA 16
#define T_LEN 2048
#define B_SZ 2
#define S_LEN 2048
#define NROW 4096            // T*B == S*B
// q pre-scale: (1/sqrt(64)) * log2(e)  -> softmax becomes exp2(score)
#define Q_SCALE 0.1803368801111204f

#define XG_N ((size_t)NROW * KAUG)
#define WG_N ((size_t)E_DIM * KAUG)
#define HSZ  ((size_t)B_SZ * N_HEADS * T_LEN * HD)

typedef unsigned short USH;
typedef __bf16 bf16x8 __attribute__((ext_vector_type(8)));
typedef float  f32x4  __attribute__((ext_vector_type(4)));

__device__ __forceinline__ USH f2bf(float f) {
    uint32_t u = __builtin_bit_cast(uint32_t, f);
    return (USH)((u + 0x7FFFu + ((u >> 16) & 1u)) >> 16);
}
__device__ __forceinline__ float bf2f(USH s) {
    uint32_t u = ((uint32_t)s) << 16;
    return __builtin_bit_cast(float, u);
}
__device__ __forceinline__ void async_cp16(const void* g, void* l) {
    __builtin_amdgcn_global_load_lds(
        (const __attribute__((address_space(1))) void*)g,
        (__attribute__((address_space(3))) void*)l, 16, 0, 0);
}
// pack hi16(x), hi16(y) -> dword (bf16 truncation; y in high half)
__device__ __forceinline__ uint32_t pack_bf_trunc(float x, float y) {
    return __builtin_amdgcn_perm(__builtin_bit_cast(uint32_t, y),
                                 __builtin_bit_cast(uint32_t, x), 0x07060302u);
}

// ---------------------------------------------------------------------------
// Fused q/k/v: write bf16(X) row into Xg[y] AND compute XA tail. grid (NROW,3)
// ---------------------------------------------------------------------------
__global__ __launch_bounds__(256) void lora_aug_x3_kernel(
    const float* __restrict__ Xq, const float* __restrict__ Xk,
    const float* __restrict__ Xv,
    const float* __restrict__ laq, const float* __restrict__ lak,
    const float* __restrict__ lav, USH* __restrict__ Xg_base) {
    int n = blockIdx.x, y = blockIdx.y, tid = threadIdx.x;
    const float* X  = (y == 0) ? Xq : (y == 1) ? Xk : Xv;
    const float* la = (y == 0) ? laq : (y == 1) ? lak : lav;
    USH* Xg = Xg_base + (size_t)y * XG_N;

    float4 xv = *(const float4*)(X + (size_t)n * E_DIM + tid * 4);
    ushort4 ox;
    ox.x = f2bf(xv.x); ox.y = f2bf(xv.y); ox.z = f2bf(xv.z); ox.w = f2bf(xv.w);
    *(ushort4*)(Xg + (size_t)n * KAUG + tid * 4) = ox;

    float acc[R_LORA];
#pragma unroll
    for (int r = 0; r < R_LORA; ++r) {
        float4 lv = *(const float4*)(la + (size_t)r * E_DIM + tid * 4);
        acc[r] = xv.x * lv.x + xv.y * lv.y + xv.z * lv.z + xv.w * lv.w;
    }
#pragma unroll
    for (int r = 0; r < R_LORA; ++r) {
        float v = acc[r];
#pragma unroll
        for (int off = 32; off > 0; off >>= 1) v += __shfl_down(v, off, 64);
        acc[r] = v;
    }
    __shared__ float red[R_LORA][4];
    int lane = tid & 63, wid = tid >> 6;
    if (lane == 0) {
#pragma unroll
        for (int r = 0; r < R_LORA; ++r) red[r][wid] = acc[r];
    }
    __syncthreads();
    if (tid < 32) {
        float v = 0.0f;
        if (tid < R_LORA) v = red[tid][0] + red[tid][1] + red[tid][2] + red[tid][3];
        else if (tid == R_LORA) v = 1.0f;
        Xg[(size_t)n * KAUG + 1024 + tid] = f2bf(v);
    }
}

// ---------------------------------------------------------------------------
// LoRA-A over bf16 rows of Xg (cols 0..1023); writes tail cols 1024..1055.
// ---------------------------------------------------------------------------
__global__ __launch_bounds__(256) void lora_a_bf16_kernel(
    USH* __restrict__ Xg, const float* __restrict__ la) {
    int n = blockIdx.x, tid = threadIdx.x;
    ushort4 xu = *(const ushort4*)(Xg + (size_t)n * KAUG + tid * 4);
    float x0 = bf2f(xu.x), x1 = bf2f(xu.y), x2 = bf2f(xu.z), x3 = bf2f(xu.w);
    float acc[R_LORA];
#pragma unroll
    for (int r = 0; r < R_LORA; ++r) {
        float4 lv = *(const float4*)(la + (size_t)r * E_DIM + tid * 4);
        acc[r] = x0 * lv.x + x1 * lv.y + x2 * lv.z + x3 * lv.w;
    }
#pragma unroll
    for (int r = 0; r < R_LORA; ++r) {
        float v = acc[r];
#pragma unroll
        for (int off = 32; off > 0; off >>= 1) v += __shfl_down(v, off, 64);
        acc[r] = v;
    }
    __shared__ float red[R_LORA][4];
    int lane = tid & 63, wid = tid >> 6;
    if (lane == 0) {
#pragma unroll
        for (int r = 0; r < R_LORA; ++r) red[r][wid] = acc[r];
    }
    __syncthreads();
    if (tid < 32) {
        float v = 0.0f;
        if (tid < R_LORA) v = red[tid][0] + red[tid][1] + red[tid][2] + red[tid][3];
        else if (tid == R_LORA) v = 1.0f;
        Xg[(size_t)n * KAUG + 1024 + tid] = f2bf(v);
    }
}

// ---------------------------------------------------------------------------
// Fused weight augment for all four projections. grid (E_DIM, 4): q,k,v,o.
// ---------------------------------------------------------------------------
__global__ __launch_bounds__(256) void aug_w4_kernel(
    const float* __restrict__ Wq, const float* __restrict__ lbq, const float* __restrict__ bq,
    const float* __restrict__ Wk, const float* __restrict__ lbk, const float* __restrict__ bk_,
    const float* __restrict__ Wv, const float* __restrict__ lbv, const float* __restrict__ bv_,
    const float* __restrict__ Wo, const float* __restrict__ lbo, const float* __restrict__ bo,
    USH* __restrict__ Wg_base) {
    int e = blockIdx.x, y = blockIdx.y, tid = threadIdx.x;
    const float* W    = (y == 0) ? Wq : (y == 1) ? Wk : (y == 2) ? Wv : Wo;
    const float* lb   = (y == 0) ? lbq : (y == 1) ? lbk : (y == 2) ? lbv : lbo;
    const float* bias = (y == 0) ? bq : (y == 1) ? bk_ : (y == 2) ? bv_ : bo;
    USH* Wg = Wg_base + (size_t)y * WG_N;

    float4 v = *(const float4*)(W + (size_t)e * E_DIM + tid * 4);
    ushort4 o;
    o.x = f2bf(v.x); o.y = f2bf(v.y); o.z = f2bf(v.z); o.w = f2bf(v.w);
    *(ushort4*)(Wg + (size_t)e * KAUG + tid * 4) = o;
    if (tid < 32) {
        float t = (tid < R_LORA) ? lb[(size_t)e * R_LORA + tid]
                                 : (tid == R_LORA ? bias[e] : 0.0f);
        Wg[(size_t)e * KAUG + 1024 + tid] = f2bf(t);
    }
}

// ---------------------------------------------------------------------------
// Batched q/k/v GEMM, 128x128 tile (16 MFMA/iter), grid (8, 32, 3) = 768.
// ---------------------------------------------------------------------------
__global__ __launch_bounds__(256) void gemm_qkv_kernel(
    const USH* __restrict__ Xg_base, const USH* __restrict__ Wg_base,
    USH* __restrict__ qkv_base) {
    __shared__ __align__(16) USH As[128 * 32];
    __shared__ __align__(16) USH Bs[128 * 32];
    int z = blockIdx.z;
    const USH* Xg = Xg_base + (size_t)z * XG_N;
    const USH* Wg = Wg_base + (size_t)z * WG_N;
    USH* out = qkv_base + (size_t)z * HSZ;
    float scale = (z == 0) ? Q_SCALE : 1.0f;

    int tid = threadIdx.x;
    int wid = tid >> 6, lane = tid & 63, quad = lane >> 4, l16 = lane & 15;
    int wm = wid & 1, wn = wid >> 1;
    int n0 = blockIdx.y * 128, e0 = blockIdx.x * 128;

    int r0 = wid * 16 + (lane >> 2);
    int k8 = (lane & 3) * 8;

    f32x4 acc[4][4];
    const f32x4 fzero = {0.f, 0.f, 0.f, 0.f};
#pragma unroll
    for (int i = 0; i < 4; ++i)
#pragma unroll
        for (int j = 0; j < 4; ++j) acc[i][j] = fzero;

    for (int kt = 0; kt < KAUG; kt += 32) {
        __syncthreads();
        async_cp16(Xg + (size_t)(n0 + r0) * KAUG + kt + k8,       As + (wid * 16) * 32);
        async_cp16(Xg + (size_t)(n0 + 64 + r0) * KAUG + kt + k8,  As + (64 + wid * 16) * 32);
        async_cp16(Wg + (size_t)(e0 + r0) * KAUG + kt + k8,       Bs + (wid * 16) * 32);
        async_cp16(Wg + (size_t)(e0 + 64 + r0) * KAUG + kt + k8,  Bs + (64 + wid * 16) * 32);
        __syncthreads();

        bf16x8 af[4], bfr[4];
#pragma unroll
        for (int i = 0; i < 4; ++i)
            af[i] = *(const bf16x8*)&As[(wm * 64 + i * 16 + l16) * 32 + quad * 8];
#pragma unroll
        for (int j = 0; j < 4; ++j)
            bfr[j] = *(const bf16x8*)&Bs[(wn * 64 + j * 16 + l16) * 32 + quad * 8];
#pragma unroll
        for (int i = 0; i < 4; ++i)
#pragma unroll
            for (int j = 0; j < 4; ++j)
                acc[i][j] = __builtin_amdgcn_mfma_f32_16x16x32_bf16(
                    af[i], bfr[j], acc[i][j], 0, 0, 0);
    }

#pragma unroll
    for (int i = 0; i < 4; ++i) {
#pragma unroll
        for (int j = 0; j < 4; ++j) {
#pragma unroll
            for (int r = 0; r < 4; ++r) {
                int nr = n0 + wm * 64 + i * 16 + quad * 4 + r;
                int ec = e0 + wn * 64 + j * 16 + l16;
                float v = acc[i][j][r] * scale;
                int b = nr & 1, h = ec >> 6, d = ec & 63;
                if (z != 2) {
                    int t = nr >> 1;
                    out[(((size_t)(b * 16 + h) * T_LEN + t) << 6) + d] = f2bf(v);
                } else {
                    int s = nr >> 1;
                    out[(((size_t)(b * 16 + h) * HD + d) << 11) + s] = f2bf(v);
                }
            }
        }
    }
}

// ---------------------------------------------------------------------------
// O-projection GEMM: 64(M) x 128(N) tile -> fp32 d_out. grid (8, 64).
// ---------------------------------------------------------------------------
__global__ __launch_bounds__(256) void gemm_o_kernel(
    const USH* __restrict__ Xg, const USH* __restrict__ Wg,
    float* __restrict__ out) {
    __shared__ __align__(16) USH As[64 * 32];
    __shared__ __align__(16) USH Bs[128 * 32];
    int n0 = blockIdx.y * 64, e0 = blockIdx.x * 128;
    int tid = threadIdx.x;
    int wid = tid >> 6, lane = tid & 63, quad = lane >> 4, l16 = lane & 15;
    int wm = wid & 1, wn = wid >> 1;
    int r0 = wid * 16 + (lane >> 2);
    int k8 = (lane & 3) * 8;

    f32x4 acc[2][4];
    const f32x4 fzero = {0.f, 0.f, 0.f, 0.f};
#pragma unroll
    for (int i = 0; i < 2; ++i)
#pragma unroll
        for (int j = 0; j < 4; ++j) acc[i][j] = fzero;

    for (int kt = 0; kt < KAUG; kt += 32) {
        __syncthreads();
        async_cp16(Xg + (size_t)(n0 + r0) * KAUG + kt + k8,       As + (wid * 16) * 32);
        async_cp16(Wg + (size_t)(e0 + r0) * KAUG + kt + k8,       Bs + (wid * 16) * 32);
        async_cp16(Wg + (size_t)(e0 + 64 + r0) * KAUG + kt + k8,  Bs + (64 + wid * 16) * 32);
        __syncthreads();

        bf16x8 af[2], bfr[4];
#pragma unroll
        for (int i = 0; i < 2; ++i)
            af[i] = *(const bf16x8*)&As[(wm * 32 + i * 16 + l16) * 32 + quad * 8];
#pragma unroll
        for (int j = 0; j < 4; ++j)
            bfr[j] = *(const bf16x8*)&Bs[(wn * 64 + j * 16 + l16) * 32 + quad * 8];
#pragma unroll
        for (int i = 0; i < 2; ++i)
#pragma unroll
            for (int j = 0; j < 4; ++j)
                acc[i][j] = __builtin_amdgcn_mfma_f32_16x16x32_bf16(
                    af[i], bfr[j], acc[i][j], 0, 0, 0);
    }

#pragma unroll
    for (int i = 0; i < 2; ++i)
#pragma unroll
        for (int j = 0; j < 4; ++j)
#pragma unroll
            for (int r = 0; r < 4; ++r) {
                int nr = n0 + wm * 32 + i * 16 + quad * 4 + r;
                int ec = e0 + wn * 64 + j * 16 + l16;
                out[(size_t)nr * E_DIM + ec] = acc[i][j][r];
            }
}

// ---------------------------------------------------------------------------
// Flash v7: BARRIER-FREE. All Q/K/V fragments loaded directly global->register
// (coalesced 16B/lane chunks); LDS only holds the wave-private P blobs, so the
// s-loop has zero __syncthreads and the compiler pipelines loads with vmcnt.
// 128 q-rows/block, 4 waves x 32 rows. Swapped-operand QK (A=K, B=Q).
// grid (T/128, B*H) = 512 blocks, 3 blocks/CU.
// ---------------------------------------------------------------------------
__global__ __launch_bounds__(256, 3) void flash_mfma_kernel(
    const USH* __restrict__ qp, const USH* __restrict__ kp,
    const USH* __restrict__ vpt, USH* __restrict__ ohg,
    float* __restrict__ lbuf) {
    __shared__ __align__(16) USH Ps[4 * 2048];   // per-wave P blobs (2 x 1024)

    int t0 = blockIdx.x * 128, bh = blockIdx.y;
    int tid = threadIdx.x, w = tid >> 6, lane = tid & 63;
    int quad = lane >> 4, l16 = lane & 15;
    int sw = l16 & 7;                          // granule xor-swizzle
    size_t headO = (size_t)bh * (T_LEN * HD);

    // Q fragments direct (B-operand: B[n=t=l16][k=d=quad*8+..])
    bf16x8 bq[2][2];
#pragma unroll
    for (int i2 = 0; i2 < 2; ++i2) {
        const USH* qrow = qp + headO + (size_t)(t0 + w * 32 + i2 * 16 + l16) * HD;
#pragma unroll
        for (int half = 0; half < 2; ++half)
            bq[i2][half] = *(const bf16x8*)(qrow + half * 32 + quad * 8);
    }

    float lsum[2] = {0.f, 0.f};
    const f32x4 fzero = {0.f, 0.f, 0.f, 0.f};
    f32x4 o[2][4];
#pragma unroll
    for (int i2 = 0; i2 < 2; ++i2)
#pragma unroll
        for (int jd = 0; jd < 4; ++jd) o[i2][jd] = fzero;

    for (int s0 = 0; s0 < S_LEN; s0 += 64) {
        // K fragments direct (A-operand: A[m=s=l16][k=d])
        bf16x8 ak[4][2];
#pragma unroll
        for (int j = 0; j < 4; ++j) {
            const USH* krow = kp + headO + (size_t)(s0 + j * 16 + l16) * HD;
#pragma unroll
            for (int half = 0; half < 2; ++half)
                ak[j][half] = *(const bf16x8*)(krow + half * 32 + quad * 8);
        }
        // V fragments direct (B-operand: B[n=d=l16][k=s])
        bf16x8 bv[4][2];
#pragma unroll
        for (int jd = 0; jd < 4; ++jd) {
            const USH* vrow = vpt + headO + (size_t)(jd * 16 + l16) * S_LEN + s0;
#pragma unroll
            for (int half = 0; half < 2; ++half)
                bv[jd][half] = *(const bf16x8*)(vrow + half * 32 + quad * 8);
        }

        // QK^T (swapped): sc[j][r] = score(t=l16, s = s0 + j*16 + quad*4 + r)
#pragma unroll
        for (int i2 = 0; i2 < 2; ++i2) {
            f32x4 sc[4];
#pragma unroll
            for (int j = 0; j < 4; ++j) {
                sc[j] = __builtin_amdgcn_mfma_f32_16x16x32_bf16(ak[j][0], bq[i2][0], fzero, 0, 0, 0);
                sc[j] = __builtin_amdgcn_mfma_f32_16x16x32_bf16(ak[j][1], bq[i2][1], sc[j], 0, 0, 0);
            }
            float ls = 0.f;
#pragma unroll
            for (int j = 0; j < 4; ++j)
#pragma unroll
                for (int r = 0; r < 4; ++r) {
                    float p = exp2f(sc[j][r]);
                    sc[j][r] = p;
                    ls += p;
                }
            lsum[i2] += ls;
            // pack P row-major and write (wave-private, no barrier)
            USH* pb = Ps + w * 2048 + i2 * 1024;
#pragma unroll
            for (int j = 0; j < 4; ++j) {
                uint2 dv;
                dv.x = pack_bf_trunc(sc[j][0], sc[j][1]);
                dv.y = pack_bf_trunc(sc[j][2], sc[j][3]);
                int g = (j * 2 + (quad >> 1)) ^ sw;
                *(uint2*)&pb[l16 * 64 + g * 8 + (quad & 1) * 4] = dv;
            }
        }

        // PV
#pragma unroll
        for (int i2 = 0; i2 < 2; ++i2) {
            const USH* pb = Ps + w * 2048 + i2 * 1024;
            bf16x8 ap0 = *(const bf16x8*)&pb[l16 * 64 + (quad ^ sw) * 8];
            bf16x8 ap1 = *(const bf16x8*)&pb[l16 * 64 + ((4 + quad) ^ sw) * 8];
#pragma unroll
            for (int jd = 0; jd < 4; ++jd) {
                o[i2][jd] = __builtin_amdgcn_mfma_f32_16x16x32_bf16(ap0, bv[jd][0], o[i2][jd], 0, 0, 0);
                o[i2][jd] = __builtin_amdgcn_mfma_f32_16x16x32_bf16(ap1, bv[jd][1], o[i2][jd], 0, 0, 0);
            }
        }
    }

    // lsum partial per quad (t = l16): reduce across quad bits
#pragma unroll
    for (int i2 = 0; i2 < 2; ++i2) {
        lsum[i2] += __shfl_xor(lsum[i2], 16, 64);
        lsum[i2] += __shfl_xor(lsum[i2], 32, 64);
    }

    int b = bh >> 4, h = bh & 15;
#pragma unroll
    for (int i2 = 0; i2 < 2; ++i2) {
        float inv[4];
#pragma unroll
        for (int r = 0; r < 4; ++r)
            inv[r] = 1.0f / __shfl(lsum[i2], (lane & 48) | (quad * 4 + r), 64);
#pragma unroll
        for (int jd = 0; jd < 4; ++jd)
#pragma unroll
            for (int r = 0; r < 4; ++r) {
                int t = t0 + w * 32 + i2 * 16 + quad * 4 + r;
                int n = t * 2 + b, e = h * 64 + jd * 16 + l16;
                ohg[(size_t)n * KAUG + e] = f2bf(o[i2][jd][r] * inv[r]);
            }
        if (quad == 0)
            lbuf[(size_t)bh * T_LEN + t0 + w * 32 + i2 * 16 + l16] = lsum[i2];
    }
}

// ---------------------------------------------------------------------------
// attnw v7: BARRIER-FREE, zero LDS. Q/K fragments direct global->register.
// 128t x 64s per block, loops 16 heads. grid (S/64, T/128, B) = 1024 blocks.
// ---------------------------------------------------------------------------
__global__ __launch_bounds__(256, 4) void attnw_mfma_kernel(
    const USH* __restrict__ qp, const USH* __restrict__ kp,
    const float* __restrict__ lbuf, float* __restrict__ aw) {
    int s0 = blockIdx.x * 64, t0 = blockIdx.y * 128, b = blockIdx.z;
    int tid = threadIdx.x, w = tid >> 6, lane = tid & 63;
    int quad = lane >> 4, l16 = lane & 15;

    const f32x4 fzero = {0.f, 0.f, 0.f, 0.f};
    f32x4 acc[2][4];
#pragma unroll
    for (int i2 = 0; i2 < 2; ++i2)
#pragma unroll
        for (int j = 0; j < 4; ++j) acc[i2][j] = fzero;

    for (int h = 0; h < N_HEADS; ++h) {
        int bh = b * 16 + h;
        size_t head = (size_t)bh * (T_LEN * HD);

        // K fragments (B-operand: B[n=s=l16][k=d])
        bf16x8 bk[4][2];
#pragma unroll
        for (int j = 0; j < 4; ++j) {
            const USH* krow = kp + head + (size_t)(s0 + j * 16 + l16) * HD;
#pragma unroll
            for (int half = 0; half < 2; ++half)
                bk[j][half] = *(const bf16x8*)(krow + half * 32 + quad * 8);
        }

        float il[2][4];
#pragma unroll
        for (int i2 = 0; i2 < 2; ++i2)
#pragma unroll
            for (int r = 0; r < 4; ++r) {
                int t = t0 + w * 32 + i2 * 16 + quad * 4 + r;
                il[i2][r] = 1.0f / lbuf[(size_t)bh * T_LEN + t];
            }

#pragma unroll
        for (int i2 = 0; i2 < 2; ++i2) {
            // Q fragments (A-operand: A[m=t=l16][k=d])
            const USH* qrow = qp + head + (size_t)(t0 + w * 32 + i2 * 16 + l16) * HD;
            bf16x8 a0 = *(const bf16x8*)(qrow + quad * 8);
            bf16x8 a1 = *(const bf16x8*)(qrow + 32 + quad * 8);
#pragma unroll
            for (int j = 0; j < 4; ++j) {
                f32x4 s = __builtin_amdgcn_mfma_f32_16x16x32_bf16(a0, bk[j][0], fzero, 0, 0, 0);
                s = __builtin_amdgcn_mfma_f32_16x16x32_bf16(a1, bk[j][1], s, 0, 0, 0);
#pragma unroll
                for (int r = 0; r < 4; ++r)
                    acc[i2][j][r] += exp2f(s[r]) * il[i2][r];
            }
        }
    }

    const float inv_h = 1.0f / (float)N_HEADS;
#pragma unroll
    for (int i2 = 0; i2 < 2; ++i2)
#pragma unroll
        for (int j = 0; j < 4; ++j)
#pragma unroll
            for (int r = 0; r < 4; ++r) {
                int t = t0 + w * 32 + i2 * 16 + quad * 4 + r;
                aw[(size_t)b * T_LEN * S_LEN + (size_t)t * S_LEN + s0 + j * 16 + l16] =
                    acc[i2][j][r] * inv_h;
            }
}

// ---------------------------------------------------------------------------
extern "C" void kernel_launch(void* const* d_in, const int* in_sizes, int n_in,
                              void* d_out, int out_size, void* d_ws, size_t ws_size,
                              hipStream_t stream) {
    (void)in_sizes; (void)n_in; (void)out_size; (void)ws_size;

    const float* query = (const float*)d_in[0];
    const float* key_  = (const float*)d_in[1];
    const float* value = (const float*)d_in[2];
    const float* q_w = (const float*)d_in[3],  *q_b = (const float*)d_in[4];
    const float* q_la = (const float*)d_in[5], *q_lb = (const float*)d_in[6];
    const float* k_w = (const float*)d_in[7],  *k_b = (const float*)d_in[8];
    const float* k_la = (const float*)d_in[9], *k_lb = (const float*)d_in[10];
    const float* v_w = (const float*)d_in[11], *v_b = (const float*)d_in[12];
    const float* v_la = (const float*)d_in[13], *v_lb = (const float*)d_in[14];
    const float* o_w = (const float*)d_in[15], *o_b = (const float*)d_in[16];
    const float* o_la = (const float*)d_in[17], *o_lb = (const float*)d_in[18];

    USH* Xg   = (USH*)d_ws;                 // 3 * NROW*KAUG
    USH* Wg   = Xg + 3 * XG_N;              // 4 * E_DIM*KAUG
    USH* qkv  = Wg + 4 * WG_N;              // 3 * HSZ
    USH* qp   = qkv;
    USH* kp   = qkv + HSZ;
    USH* vpt  = qkv + 2 * HSZ;
    float* lbuf = (float*)(qkv + 3 * HSZ);

    float* out = (float*)d_out;                       // (T,B,E) fp32
    float* aw  = out + (size_t)T_LEN * B_SZ * E_DIM;  // (B,T,S) fp32

    dim3 blk(256);

    lora_aug_x3_kernel<<<dim3(NROW, 3), blk, 0, stream>>>(
        query, key_, value, q_la, k_la, v_la, Xg);
    aug_w4_kernel<<<dim3(E_DIM, 4), blk, 0, stream>>>(
        q_w, q_lb, q_b, k_w, k_lb, k_b, v_w, v_lb, v_b, o_w, o_lb, o_b, Wg);
    gemm_qkv_kernel<<<dim3(E_DIM / 128, NROW / 128, 3), blk, 0, stream>>>(Xg, Wg, qkv);

    flash_mfma_kernel<<<dim3(T_LEN / 128, B_SZ * N_HEADS), blk, 0, stream>>>(
        qp, kp, vpt, Xg, lbuf);
    attnw_mfma_kernel<<<dim3(S_LEN / 64, T_LEN / 128, B_SZ), blk, 0, stream>>>(
        qp, kp, lbuf, aw);

    lora_a_bf16_kernel<<<NROW, blk, 0, stream>>>(Xg, o_la);
    gemm_o_kernel<<<dim3(E_DIM / 128, NROW / 64), blk, 0, stream>>>(
        Xg, Wg + 3 * WG_N, out);
}

// Round 9
// 421.648 us; speedup vs baseline: 1.1712x; 1.1712x over previous
//
#include <hip/hip_runtime.h>
#include <stdint.h>

// Problem constants
#define E_DIM 1024
#define KAUG 1056            // 1024 + 16 (LoRA) + 1 (bias) + 15 pad
#define N_HEADS 16
#define HD 64
#define R_LORA 16
#define T_LEN 2048
#define B_SZ 2
#define S_LEN 2048
#define NROW 4096            // T*B == S*B
// q pre-scale: (1/sqrt(64)) * log2(e)  -> softmax becomes exp2(score)
#define Q_SCALE 0.1803368801111204f

#define XG_N ((size_t)NROW * KAUG)
#define WG_N ((size_t)E_DIM * KAUG)
#define HSZ  ((size_t)B_SZ * N_HEADS * T_LEN * HD)

typedef unsigned short USH;
typedef __bf16 bf16x8 __attribute__((ext_vector_type(8)));
typedef float  f32x4  __attribute__((ext_vector_type(4)));

__device__ __forceinline__ USH f2bf(float f) {
    uint32_t u = __builtin_bit_cast(uint32_t, f);
    return (USH)((u + 0x7FFFu + ((u >> 16) & 1u)) >> 16);
}
__device__ __forceinline__ float bf2f(USH s) {
    uint32_t u = ((uint32_t)s) << 16;
    return __builtin_bit_cast(float, u);
}
__device__ __forceinline__ void async_cp16(const void* g, void* l) {
    __builtin_amdgcn_global_load_lds(
        (const __attribute__((address_space(1))) void*)g,
        (__attribute__((address_space(3))) void*)l, 16, 0, 0);
}
// pack hi16(x), hi16(y) -> dword (bf16 truncation; y in high half)
__device__ __forceinline__ uint32_t pack_bf_trunc(float x, float y) {
    return __builtin_amdgcn_perm(__builtin_bit_cast(uint32_t, y),
                                 __builtin_bit_cast(uint32_t, x), 0x07060302u);
}

// ---------------------------------------------------------------------------
// Fused q/k/v: write bf16(X) row into Xg[y] AND compute XA tail. grid (NROW,3)
// ---------------------------------------------------------------------------
__global__ __launch_bounds__(256) void lora_aug_x3_kernel(
    const float* __restrict__ Xq, const float* __restrict__ Xk,
    const float* __restrict__ Xv,
    const float* __restrict__ laq, const float* __restrict__ lak,
    const float* __restrict__ lav, USH* __restrict__ Xg_base) {
    int n = blockIdx.x, y = blockIdx.y, tid = threadIdx.x;
    const float* X  = (y == 0) ? Xq : (y == 1) ? Xk : Xv;
    const float* la = (y == 0) ? laq : (y == 1) ? lak : lav;
    USH* Xg = Xg_base + (size_t)y * XG_N;

    float4 xv = *(const float4*)(X + (size_t)n * E_DIM + tid * 4);
    ushort4 ox;
    ox.x = f2bf(xv.x); ox.y = f2bf(xv.y); ox.z = f2bf(xv.z); ox.w = f2bf(xv.w);
    *(ushort4*)(Xg + (size_t)n * KAUG + tid * 4) = ox;

    float acc[R_LORA];
#pragma unroll
    for (int r = 0; r < R_LORA; ++r) {
        float4 lv = *(const float4*)(la + (size_t)r * E_DIM + tid * 4);
        acc[r] = xv.x * lv.x + xv.y * lv.y + xv.z * lv.z + xv.w * lv.w;
    }
#pragma unroll
    for (int r = 0; r < R_LORA; ++r) {
        float v = acc[r];
#pragma unroll
        for (int off = 32; off > 0; off >>= 1) v += __shfl_down(v, off, 64);
        acc[r] = v;
    }
    __shared__ float red[R_LORA][4];
    int lane = tid & 63, wid = tid >> 6;
    if (lane == 0) {
#pragma unroll
        for (int r = 0; r < R_LORA; ++r) red[r][wid] = acc[r];
    }
    __syncthreads();
    if (tid < 32) {
        float v = 0.0f;
        if (tid < R_LORA) v = red[tid][0] + red[tid][1] + red[tid][2] + red[tid][3];
        else if (tid == R_LORA) v = 1.0f;
        Xg[(size_t)n * KAUG + 1024 + tid] = f2bf(v);
    }
}

// ---------------------------------------------------------------------------
// LoRA-A over bf16 rows of Xg (cols 0..1023); writes tail cols 1024..1055.
// ---------------------------------------------------------------------------
__global__ __launch_bounds__(256) void lora_a_bf16_kernel(
    USH* __restrict__ Xg, const float* __restrict__ la) {
    int n = blockIdx.x, tid = threadIdx.x;
    ushort4 xu = *(const ushort4*)(Xg + (size_t)n * KAUG + tid * 4);
    float x0 = bf2f(xu.x), x1 = bf2f(xu.y), x2 = bf2f(xu.z), x3 = bf2f(xu.w);
    float acc[R_LORA];
#pragma unroll
    for (int r = 0; r < R_LORA; ++r) {
        float4 lv = *(const float4*)(la + (size_t)r * E_DIM + tid * 4);
        acc[r] = x0 * lv.x + x1 * lv.y + x2 * lv.z + x3 * lv.w;
    }
#pragma unroll
    for (int r = 0; r < R_LORA; ++r) {
        float v = acc[r];
#pragma unroll
        for (int off = 32; off > 0; off >>= 1) v += __shfl_down(v, off, 64);
        acc[r] = v;
    }
    __shared__ float red[R_LORA][4];
    int lane = tid & 63, wid = tid >> 6;
    if (lane == 0) {
#pragma unroll
        for (int r = 0; r < R_LORA; ++r) red[r][wid] = acc[r];
    }
    __syncthreads();
    if (tid < 32) {
        float v = 0.0f;
        if (tid < R_LORA) v = red[tid][0] + red[tid][1] + red[tid][2] + red[tid][3];
        else if (tid == R_LORA) v = 1.0f;
        Xg[(size_t)n * KAUG + 1024 + tid] = f2bf(v);
    }
}

// ---------------------------------------------------------------------------
// Fused weight augment for all four projections. grid (E_DIM, 4): q,k,v,o.
// ---------------------------------------------------------------------------
__global__ __launch_bounds__(256) void aug_w4_kernel(
    const float* __restrict__ Wq, const float* __restrict__ lbq, const float* __restrict__ bq,
    const float* __restrict__ Wk, const float* __restrict__ lbk, const float* __restrict__ bk_,
    const float* __restrict__ Wv, const float* __restrict__ lbv, const float* __restrict__ bv_,
    const float* __restrict__ Wo, const float* __restrict__ lbo, const float* __restrict__ bo,
    USH* __restrict__ Wg_base) {
    int e = blockIdx.x, y = blockIdx.y, tid = threadIdx.x;
    const float* W    = (y == 0) ? Wq : (y == 1) ? Wk : (y == 2) ? Wv : Wo;
    const float* lb   = (y == 0) ? lbq : (y == 1) ? lbk : (y == 2) ? lbv : lbo;
    const float* bias = (y == 0) ? bq : (y == 1) ? bk_ : (y == 2) ? bv_ : bo;
    USH* Wg = Wg_base + (size_t)y * WG_N;

    float4 v = *(const float4*)(W + (size_t)e * E_DIM + tid * 4);
    ushort4 o;
    o.x = f2bf(v.x); o.y = f2bf(v.y); o.z = f2bf(v.z); o.w = f2bf(v.w);
    *(ushort4*)(Wg + (size_t)e * KAUG + tid * 4) = o;
    if (tid < 32) {
        float t = (tid < R_LORA) ? lb[(size_t)e * R_LORA + tid]
                                 : (tid == R_LORA ? bias[e] : 0.0f);
        Wg[(size_t)e * KAUG + 1024 + tid] = f2bf(t);
    }
}

// ---------------------------------------------------------------------------
// Batched q/k/v GEMM, 128x128 tile (16 MFMA/iter), grid (8, 32, 3) = 768.
// ---------------------------------------------------------------------------
__global__ __launch_bounds__(256) void gemm_qkv_kernel(
    const USH* __restrict__ Xg_base, const USH* __restrict__ Wg_base,
    USH* __restrict__ qkv_base) {
    __shared__ __align__(16) USH As[128 * 32];
    __shared__ __align__(16) USH Bs[128 * 32];
    int z = blockIdx.z;
    const USH* Xg = Xg_base + (size_t)z * XG_N;
    const USH* Wg = Wg_base + (size_t)z * WG_N;
    USH* out = qkv_base + (size_t)z * HSZ;
    float scale = (z == 0) ? Q_SCALE : 1.0f;

    int tid = threadIdx.x;
    int wid = tid >> 6, lane = tid & 63, quad = lane >> 4, l16 = lane & 15;
    int wm = wid & 1, wn = wid >> 1;
    int n0 = blockIdx.y * 128, e0 = blockIdx.x * 128;

    int r0 = wid * 16 + (lane >> 2);
    int k8 = (lane & 3) * 8;

    f32x4 acc[4][4];
    const f32x4 fzero = {0.f, 0.f, 0.f, 0.f};
#pragma unroll
    for (int i = 0; i < 4; ++i)
#pragma unroll
        for (int j = 0; j < 4; ++j) acc[i][j] = fzero;

    for (int kt = 0; kt < KAUG; kt += 32) {
        __syncthreads();
        async_cp16(Xg + (size_t)(n0 + r0) * KAUG + kt + k8,       As + (wid * 16) * 32);
        async_cp16(Xg + (size_t)(n0 + 64 + r0) * KAUG + kt + k8,  As + (64 + wid * 16) * 32);
        async_cp16(Wg + (size_t)(e0 + r0) * KAUG + kt + k8,       Bs + (wid * 16) * 32);
        async_cp16(Wg + (size_t)(e0 + 64 + r0) * KAUG + kt + k8,  Bs + (64 + wid * 16) * 32);
        __syncthreads();

        bf16x8 af[4], bfr[4];
#pragma unroll
        for (int i = 0; i < 4; ++i)
            af[i] = *(const bf16x8*)&As[(wm * 64 + i * 16 + l16) * 32 + quad * 8];
#pragma unroll
        for (int j = 0; j < 4; ++j)
            bfr[j] = *(const bf16x8*)&Bs[(wn * 64 + j * 16 + l16) * 32 + quad * 8];
#pragma unroll
        for (int i = 0; i < 4; ++i)
#pragma unroll
            for (int j = 0; j < 4; ++j)
                acc[i][j] = __builtin_amdgcn_mfma_f32_16x16x32_bf16(
                    af[i], bfr[j], acc[i][j], 0, 0, 0);
    }

#pragma unroll
    for (int i = 0; i < 4; ++i) {
#pragma unroll
        for (int j = 0; j < 4; ++j) {
#pragma unroll
            for (int r = 0; r < 4; ++r) {
                int nr = n0 + wm * 64 + i * 16 + quad * 4 + r;
                int ec = e0 + wn * 64 + j * 16 + l16;
                float v = acc[i][j][r] * scale;
                int b = nr & 1, h = ec >> 6, d = ec & 63;
                if (z != 2) {
                    int t = nr >> 1;
                    out[(((size_t)(b * 16 + h) * T_LEN + t) << 6) + d] = f2bf(v);
                } else {
                    int s = nr >> 1;
                    out[(((size_t)(b * 16 + h) * HD + d) << 11) + s] = f2bf(v);
                }
            }
        }
    }
}

// ---------------------------------------------------------------------------
// O-projection GEMM: 64(M) x 128(N) tile -> fp32 d_out. grid (8, 64).
// ---------------------------------------------------------------------------
__global__ __launch_bounds__(256) void gemm_o_kernel(
    const USH* __restrict__ Xg, const USH* __restrict__ Wg,
    float* __restrict__ out) {
    __shared__ __align__(16) USH As[64 * 32];
    __shared__ __align__(16) USH Bs[128 * 32];
    int n0 = blockIdx.y * 64, e0 = blockIdx.x * 128;
    int tid = threadIdx.x;
    int wid = tid >> 6, lane = tid & 63, quad = lane >> 4, l16 = lane & 15;
    int wm = wid & 1, wn = wid >> 1;
    int r0 = wid * 16 + (lane >> 2);
    int k8 = (lane & 3) * 8;

    f32x4 acc[2][4];
    const f32x4 fzero = {0.f, 0.f, 0.f, 0.f};
#pragma unroll
    for (int i = 0; i < 2; ++i)
#pragma unroll
        for (int j = 0; j < 4; ++j) acc[i][j] = fzero;

    for (int kt = 0; kt < KAUG; kt += 32) {
        __syncthreads();
        async_cp16(Xg + (size_t)(n0 + r0) * KAUG + kt + k8,       As + (wid * 16) * 32);
        async_cp16(Wg + (size_t)(e0 + r0) * KAUG + kt + k8,       Bs + (wid * 16) * 32);
        async_cp16(Wg + (size_t)(e0 + 64 + r0) * KAUG + kt + k8,  Bs + (64 + wid * 16) * 32);
        __syncthreads();

        bf16x8 af[2], bfr[4];
#pragma unroll
        for (int i = 0; i < 2; ++i)
            af[i] = *(const bf16x8*)&As[(wm * 32 + i * 16 + l16) * 32 + quad * 8];
#pragma unroll
        for (int j = 0; j < 4; ++j)
            bfr[j] = *(const bf16x8*)&Bs[(wn * 64 + j * 16 + l16) * 32 + quad * 8];
#pragma unroll
        for (int i = 0; i < 2; ++i)
#pragma unroll
            for (int j = 0; j < 4; ++j)
                acc[i][j] = __builtin_amdgcn_mfma_f32_16x16x32_bf16(
                    af[i], bfr[j], acc[i][j], 0, 0, 0);
    }

#pragma unroll
    for (int i = 0; i < 2; ++i)
#pragma unroll
        for (int j = 0; j < 4; ++j)
#pragma unroll
            for (int r = 0; r < 4; ++r) {
                int nr = n0 + wm * 32 + i * 16 + quad * 4 + r;
                int ec = e0 + wn * 64 + j * 16 + l16;
                out[(size_t)nr * E_DIM + ec] = acc[i][j][r];
            }
}

// ---------------------------------------------------------------------------
// Flash v9: round-7 structure (LDS staging, swapped-operand QK, wave-private
// P blobs) but 2-WAVE BLOCKS (128 thr), 64 q-rows/tile, wave = 32 rows.
// grid (T/64, B*H) = 1024 blocks -> ~6 blocks/CU, 6 barrier groups.
// ---------------------------------------------------------------------------
__global__ __launch_bounds__(128, 3) void flash_mfma_kernel(
    const USH* __restrict__ qp, const USH* __restrict__ kp,
    const USH* __restrict__ vpt, USH* __restrict__ ohg,
    float* __restrict__ lbuf) {
    __shared__ __align__(16) USH QPs[4096];   // Q tile 64x64, then P blobs (2x2048)
    __shared__ __align__(16) USH Ks[4096];
    __shared__ __align__(16) USH Vs[4096];

    int t0 = blockIdx.x * 64, bh = blockIdx.y;
    int tid = threadIdx.x, w = tid >> 6, lane = tid & 63;
    int quad = lane >> 4, l16 = lane & 15;
    int sw = l16 & 7;                          // granule xor-swizzle
    size_t headO = (size_t)bh * (T_LEN * HD);

    // stage Q: wave w stages rows w*32 .. w*32+31 (i-blocks 2w, 2w+1)
#pragma unroll
    for (int ii = 0; ii < 2; ++ii) {
        int i = w * 2 + ii;
#pragma unroll
        for (int half = 0; half < 2; ++half)
            async_cp16(qp + headO + (size_t)(t0 + i * 16 + l16) * HD + half * 32 + quad * 8,
                       QPs + i * 1024 + half * 512);
    }
    __syncthreads();
    // register-cache Q fragments (B-operand: B[n=t=l16][k=d=quad*8+..])
    bf16x8 bq[2][2];
#pragma unroll
    for (int i2 = 0; i2 < 2; ++i2)
#pragma unroll
        for (int half = 0; half < 2; ++half)
            bq[i2][half] = *(const bf16x8*)&QPs[(w * 2 + i2) * 1024 + half * 512 + quad * 128 + l16 * 8];

    float lsum[2] = {0.f, 0.f};
    const f32x4 fzero = {0.f, 0.f, 0.f, 0.f};
    f32x4 o[2][4];
#pragma unroll
    for (int i2 = 0; i2 < 2; ++i2)
#pragma unroll
        for (int jd = 0; jd < 4; ++jd) o[i2][jd] = fzero;

    for (int s0 = 0; s0 < S_LEN; s0 += 64) {
        __syncthreads();   // both waves done reading prev K/V
        // each wave stages K j-blocks {2w, 2w+1} and V jd-blocks {2w, 2w+1}
#pragma unroll
        for (int ii = 0; ii < 2; ++ii) {
            int jb = w * 2 + ii;
#pragma unroll
            for (int half = 0; half < 2; ++half) {
                async_cp16(kp + headO + (size_t)(s0 + jb * 16 + l16) * HD + half * 32 + quad * 8,
                           Ks + jb * 1024 + half * 512);
                async_cp16(vpt + headO + (size_t)(jb * 16 + l16) * S_LEN + s0 + half * 32 + quad * 8,
                           Vs + jb * 1024 + half * 512);
            }
        }
        __syncthreads();   // drain async

        // K fragments (A-operand: A[m=s=l16][k=d]), shared across both row-blocks
        bf16x8 ak[4][2];
#pragma unroll
        for (int j = 0; j < 4; ++j)
#pragma unroll
            for (int half = 0; half < 2; ++half)
                ak[j][half] = *(const bf16x8*)&Ks[j * 1024 + half * 512 + quad * 128 + l16 * 8];

        // QK^T (swapped): sc[j][r] = score(t=l16, s = s0 + j*16 + quad*4 + r)
#pragma unroll
        for (int i2 = 0; i2 < 2; ++i2) {
            f32x4 sc[4];
#pragma unroll
            for (int j = 0; j < 4; ++j) {
                sc[j] = __builtin_amdgcn_mfma_f32_16x16x32_bf16(ak[j][0], bq[i2][0], fzero, 0, 0, 0);
                sc[j] = __builtin_amdgcn_mfma_f32_16x16x32_bf16(ak[j][1], bq[i2][1], sc[j], 0, 0, 0);
            }
            float ls = 0.f;
#pragma unroll
            for (int j = 0; j < 4; ++j)
#pragma unroll
                for (int r = 0; r < 4; ++r) {
                    float p = exp2f(sc[j][r]);
                    sc[j][r] = p;
                    ls += p;
                }
            lsum[i2] += ls;
            // pack P row-major and write (wave-private, no barrier)
            USH* pb = QPs + w * 2048 + i2 * 1024;
#pragma unroll
            for (int j = 0; j < 4; ++j) {
                uint2 dv;
                dv.x = pack_bf_trunc(sc[j][0], sc[j][1]);
                dv.y = pack_bf_trunc(sc[j][2], sc[j][3]);
                int g = (j * 2 + (quad >> 1)) ^ sw;
                *(uint2*)&pb[l16 * 64 + g * 8 + (quad & 1) * 4] = dv;
            }
        }

        // V fragments (B-operand: B[n=d=l16][k=s])
        bf16x8 bv[4][2];
#pragma unroll
        for (int jd = 0; jd < 4; ++jd)
#pragma unroll
            for (int half = 0; half < 2; ++half)
                bv[jd][half] = *(const bf16x8*)&Vs[jd * 1024 + half * 512 + quad * 128 + l16 * 8];

        // PV
#pragma unroll
        for (int i2 = 0; i2 < 2; ++i2) {
            const USH* pb = QPs + w * 2048 + i2 * 1024;
            bf16x8 ap0 = *(const bf16x8*)&pb[l16 * 64 + (quad ^ sw) * 8];
            bf16x8 ap1 = *(const bf16x8*)&pb[l16 * 64 + ((4 + quad) ^ sw) * 8];
#pragma unroll
            for (int jd = 0; jd < 4; ++jd) {
                o[i2][jd] = __builtin_amdgcn_mfma_f32_16x16x32_bf16(ap0, bv[jd][0], o[i2][jd], 0, 0, 0);
                o[i2][jd] = __builtin_amdgcn_mfma_f32_16x16x32_bf16(ap1, bv[jd][1], o[i2][jd], 0, 0, 0);
            }
        }
    }

    // lsum partial per quad (t = l16): reduce across quad bits
#pragma unroll
    for (int i2 = 0; i2 < 2; ++i2) {
        lsum[i2] += __shfl_xor(lsum[i2], 16, 64);
        lsum[i2] += __shfl_xor(lsum[i2], 32, 64);
    }

    int b = bh >> 4, h = bh & 15;
#pragma unroll
    for (int i2 = 0; i2 < 2; ++i2) {
        float inv[4];
#pragma unroll
        for (int r = 0; r < 4; ++r)
            inv[r] = 1.0f / __shfl(lsum[i2], (lane & 48) | (quad * 4 + r), 64);
#pragma unroll
        for (int jd = 0; jd < 4; ++jd)
#pragma unroll
            for (int r = 0; r < 4; ++r) {
                int t = t0 + w * 32 + i2 * 16 + quad * 4 + r;
                int n = t * 2 + b, e = h * 64 + jd * 16 + l16;
                ohg[(size_t)n * KAUG + e] = f2bf(o[i2][jd][r] * inv[r]);
            }
        if (quad == 0)
            lbuf[(size_t)bh * T_LEN + t0 + w * 32 + i2 * 16 + l16] = lsum[i2];
    }
}

// ---------------------------------------------------------------------------
// attnw (round-7 known-good): 128t x 64s per block, LDS staging, 16 heads.
// grid (S/64, T/128, B) = 1024 blocks.
// ---------------------------------------------------------------------------
__global__ __launch_bounds__(256, 4) void attnw_mfma_kernel(
    const USH* __restrict__ qp, const USH* __restrict__ kp,
    const float* __restrict__ lbuf, float* __restrict__ aw) {
    __shared__ __align__(16) USH Qs[8192];
    __shared__ __align__(16) USH Ks[4096];

    int s0 = blockIdx.x * 64, t0 = blockIdx.y * 128, b = blockIdx.z;
    int tid = threadIdx.x, w = tid >> 6, lane = tid & 63;
    int quad = lane >> 4, l16 = lane & 15;

    const f32x4 fzero = {0.f, 0.f, 0.f, 0.f};
    f32x4 acc[2][4];
#pragma unroll
    for (int i2 = 0; i2 < 2; ++i2)
#pragma unroll
        for (int j = 0; j < 4; ++j) acc[i2][j] = fzero;

    for (int h = 0; h < N_HEADS; ++h) {
        int bh = b * 16 + h;
        size_t head = (size_t)bh * (T_LEN * HD);
        __syncthreads();
#pragma unroll
        for (int ii = 0; ii < 2; ++ii) {
            int i = w * 2 + ii;
#pragma unroll
            for (int half = 0; half < 2; ++half)
                async_cp16(qp + head + (size_t)(t0 + i * 16 + l16) * HD + half * 32 + quad * 8,
                           Qs + i * 1024 + half * 512);
        }
#pragma unroll
        for (int half = 0; half < 2; ++half)
            async_cp16(kp + head + (size_t)(s0 + w * 16 + l16) * HD + half * 32 + quad * 8,
                       Ks + w * 1024 + half * 512);
        __syncthreads();

        float il[2][4];
#pragma unroll
        for (int i2 = 0; i2 < 2; ++i2)
#pragma unroll
            for (int r = 0; r < 4; ++r) {
                int t = t0 + w * 32 + i2 * 16 + quad * 4 + r;
                il[i2][r] = 1.0f / lbuf[(size_t)bh * T_LEN + t];
            }

        bf16x8 bk[4][2];
#pragma unroll
        for (int j = 0; j < 4; ++j)
#pragma unroll
            for (int half = 0; half < 2; ++half)
                bk[j][half] = *(const bf16x8*)&Ks[j * 1024 + half * 512 + quad * 128 + l16 * 8];

#pragma unroll
        for (int i2 = 0; i2 < 2; ++i2) {
            int i = w * 2 + i2;
            bf16x8 a0 = *(const bf16x8*)&Qs[i * 1024 + quad * 128 + l16 * 8];
            bf16x8 a1 = *(const bf16x8*)&Qs[i * 1024 + 512 + quad * 128 + l16 * 8];
#pragma unroll
            for (int j = 0; j < 4; ++j) {
                f32x4 s = __builtin_amdgcn_mfma_f32_16x16x32_bf16(a0, bk[j][0], fzero, 0, 0, 0);
                s = __builtin_amdgcn_mfma_f32_16x16x32_bf16(a1, bk[j][1], s, 0, 0, 0);
#pragma unroll
                for (int r = 0; r < 4; ++r)
                    acc[i2][j][r] += exp2f(s[r]) * il[i2][r];
            }
        }
    }

    const float inv_h = 1.0f / (float)N_HEADS;
#pragma unroll
    for (int i2 = 0; i2 < 2; ++i2)
#pragma unroll
        for (int j = 0; j < 4; ++j)
#pragma unroll
            for (int r = 0; r < 4; ++r) {
                int t = t0 + w * 32 + i2 * 16 + quad * 4 + r;
                aw[(size_t)b * T_LEN * S_LEN + (size_t)t * S_LEN + s0 + j * 16 + l16] =
                    acc[i2][j][r] * inv_h;
            }
}

// ---------------------------------------------------------------------------
extern "C" void kernel_launch(void* const* d_in, const int* in_sizes, int n_in,
                              void* d_out, int out_size, void* d_ws, size_t ws_size,
                              hipStream_t stream) {
    (void)in_sizes; (void)n_in; (void)out_size; (void)ws_size;

    const float* query = (const float*)d_in[0];
    const float* key_  = (const float*)d_in[1];
    const float* value = (const float*)d_in[2];
    const float* q_w = (const float*)d_in[3],  *q_b = (const float*)d_in[4];
    const float* q_la = (const float*)d_in[5], *q_lb = (const float*)d_in[6];
    const float* k_w = (const float*)d_in[7],  *k_b = (const float*)d_in[8];
    const float* k_la = (const float*)d_in[9], *k_lb = (const float*)d_in[10];
    const float* v_w = (const float*)d_in[11], *v_b = (const float*)d_in[12];
    const float* v_la = (const float*)d_in[13], *v_lb = (const float*)d_in[14];
    const float* o_w = (const float*)d_in[15], *o_b = (const float*)d_in[16];
    const float* o_la = (const float*)d_in[17], *o_lb = (const float*)d_in[18];

    USH* Xg   = (USH*)d_ws;                 // 3 * NROW*KAUG
    USH* Wg   = Xg + 3 * XG_N;              // 4 * E_DIM*KAUG
    USH* qkv  = Wg + 4 * WG_N;              // 3 * HSZ
    USH* qp   = qkv;
    USH* kp   = qkv + HSZ;
    USH* vpt  = qkv + 2 * HSZ;
    float* lbuf = (float*)(qkv + 3 * HSZ);

    float* out = (float*)d_out;                       // (T,B,E) fp32
    float* aw  = out + (size_t)T_LEN * B_SZ * E_DIM;  // (B,T,S) fp32

    dim3 blk(256);

    lora_aug_x3_kernel<<<dim3(NROW, 3), blk, 0, stream>>>(
        query, key_, value, q_la, k_la, v_la, Xg);
    aug_w4_kernel<<<dim3(E_DIM, 4), blk, 0, stream>>>(
        q_w, q_lb, q_b, k_w, k_lb, k_b, v_w, v_lb, v_b, o_w, o_lb, o_b, Wg);
    gemm_qkv_kernel<<<dim3(E_DIM / 128, NROW / 128, 3), blk, 0, stream>>>(Xg, Wg, qkv);

    flash_mfma_kernel<<<dim3(T_LEN / 64, B_SZ * N_HEADS), dim3(128), 0, stream>>>(
        qp, kp, vpt, Xg, lbuf);
    attnw_mfma_kernel<<<dim3(S_LEN / 64, T_LEN / 128, B_SZ), blk, 0, stream>>>(
        qp, kp, lbuf, aw);

    lora_a_bf16_kernel<<<NROW, blk, 0, stream>>>(Xg, o_la);
    gemm_o_kernel<<<dim3(E_DIM / 128, NROW / 64), blk, 0, stream>>>(
        Xg, Wg + 3 * WG_N, out);
}